// Round 1
// baseline (282.806 us; speedup 1.0000x reference)
//
#include <hip/hip_runtime.h>

#define VOCAB 5000

// ---------------------------------------------------------------------------
// Kernel 1: tiled transpose  WT[i][j] = W[j][i]
// 32x32 tile, 32x8 threads, LDS padded +1 to kill bank conflicts.
// ---------------------------------------------------------------------------
__global__ void transpose_kernel(const float* __restrict__ W,
                                 float* __restrict__ WT) {
    __shared__ float tile[32][33];
    const int bx = blockIdx.x * 32;   // source column base
    const int by = blockIdx.y * 32;   // source row base
    const int tx = threadIdx.x;       // 0..31
    const int ty = threadIdx.y;       // 0..7

#pragma unroll
    for (int k = 0; k < 4; ++k) {
        const int r = by + ty + k * 8;
        const int c = bx + tx;
        if (r < VOCAB && c < VOCAB)
            tile[ty + k * 8][tx] = W[(size_t)r * VOCAB + c];
    }
    __syncthreads();
#pragma unroll
    for (int k = 0; k < 4; ++k) {
        const int r = bx + ty + k * 8;   // row in WT = column in W
        const int c = by + tx;           // col in WT = row in W
        if (r < VOCAB && c < VOCAB)
            WT[(size_t)r * VOCAB + c] = tile[tx][ty + k * 8];
    }
}

// ---------------------------------------------------------------------------
// Kernel 2: coalesced row gather.  out[p, :] = WT[idx[p], :]
// One block per position; float4 copy (5000 = 1250 * 4, rows 16B-aligned).
// ---------------------------------------------------------------------------
__global__ void gather_rows_kernel(const float* __restrict__ WT,
                                   const int* __restrict__ idx,
                                   float* __restrict__ out) {
    const int p = blockIdx.x;
    const int token = idx[p];  // scalar load, broadcast to wave
    const float4* __restrict__ src =
        reinterpret_cast<const float4*>(WT + (size_t)token * VOCAB);
    float4* __restrict__ dst =
        reinterpret_cast<float4*>(out + (size_t)p * VOCAB);
    constexpr int N4 = VOCAB / 4;  // 1250
    for (int i = threadIdx.x; i < N4; i += blockDim.x)
        dst[i] = src[i];
}

// ---------------------------------------------------------------------------
// Fallback (ws too small): direct column gather, correct but strided reads.
// ---------------------------------------------------------------------------
__global__ void gather_cols_kernel(const float* __restrict__ W,
                                   const int* __restrict__ idx,
                                   float* __restrict__ out) {
    const int p = blockIdx.x;
    const int token = idx[p];
    for (int v = threadIdx.x; v < VOCAB; v += blockDim.x)
        out[(size_t)p * VOCAB + v] = W[(size_t)v * VOCAB + token];
}

extern "C" void kernel_launch(void* const* d_in, const int* in_sizes, int n_in,
                              void* d_out, int out_size, void* d_ws, size_t ws_size,
                              hipStream_t stream) {
    const int*   x = (const int*)d_in[0];     // [B*T] token ids
    const float* W = (const float*)d_in[1];   // [VOCAB, VOCAB] fp32
    float* out = (float*)d_out;               // [B*T, VOCAB] fp32
    const int npos = in_sizes[0];             // 32768

    const size_t wt_bytes = (size_t)VOCAB * VOCAB * sizeof(float);

    if (ws_size >= wt_bytes) {
        float* WT = (float*)d_ws;
        dim3 tb(32, 8);
        dim3 tg((VOCAB + 31) / 32, (VOCAB + 31) / 32);
        transpose_kernel<<<tg, tb, 0, stream>>>(W, WT);
        gather_rows_kernel<<<npos, 256, 0, stream>>>(WT, x, out);
    } else {
        gather_cols_kernel<<<npos, 256, 0, stream>>>(W, x, out);
    }
}

// Round 2
// 238.539 us; speedup vs baseline: 1.1856x; 1.1856x over previous
//
#include <hip/hip_runtime.h>

#define VOCAB 5000

typedef float f32x4 __attribute__((ext_vector_type(4)));

// ---------------------------------------------------------------------------
// Kernel 1: tiled transpose  WT[i][j] = W[j][i]
// 32x32 tile, 32x8 threads, LDS padded +1 to kill bank conflicts.
// Normal (caching) stores: we WANT WT resident in L2/L3 for the gather.
// ---------------------------------------------------------------------------
__global__ void transpose_kernel(const float* __restrict__ W,
                                 float* __restrict__ WT) {
    __shared__ float tile[32][33];
    const int bx = blockIdx.x * 32;   // source column base
    const int by = blockIdx.y * 32;   // source row base
    const int tx = threadIdx.x;       // 0..31
    const int ty = threadIdx.y;       // 0..7

#pragma unroll
    for (int k = 0; k < 4; ++k) {
        const int r = by + ty + k * 8;
        const int c = bx + tx;
        if (r < VOCAB && c < VOCAB)
            tile[ty + k * 8][tx] = W[(size_t)r * VOCAB + c];
    }
    __syncthreads();
#pragma unroll
    for (int k = 0; k < 4; ++k) {
        const int r = bx + ty + k * 8;   // row in WT = column in W
        const int c = by + tx;           // col in WT = row in W
        if (r < VOCAB && c < VOCAB)
            WT[(size_t)r * VOCAB + c] = tile[tx][ty + k * 8];
    }
}

// ---------------------------------------------------------------------------
// Kernel 2: coalesced row gather.  out[p, :] = WT[idx[p], :]
// One block per position; float4 copy (5000 = 1250 * 4, rows 16B-aligned).
// Non-temporal stores on `out`: the 655 MB output stream must not evict
// the 100 MB WT working set from L2/L3 (reads of WT should stay cache-hits).
// ---------------------------------------------------------------------------
__global__ void gather_rows_kernel(const float* __restrict__ WT,
                                   const int* __restrict__ idx,
                                   float* __restrict__ out) {
    const int p = blockIdx.x;
    const int token = idx[p];  // scalar load, broadcast to wave
    const f32x4* __restrict__ src =
        reinterpret_cast<const f32x4*>(WT + (size_t)token * VOCAB);
    f32x4* __restrict__ dst =
        reinterpret_cast<f32x4*>(out + (size_t)p * VOCAB);
    constexpr int N4 = VOCAB / 4;  // 1250
    for (int i = threadIdx.x; i < N4; i += blockDim.x) {
        f32x4 v = src[i];
        __builtin_nontemporal_store(v, &dst[i]);
    }
}

// ---------------------------------------------------------------------------
// Fallback (ws too small): direct column gather, correct but strided reads.
// ---------------------------------------------------------------------------
__global__ void gather_cols_kernel(const float* __restrict__ W,
                                   const int* __restrict__ idx,
                                   float* __restrict__ out) {
    const int p = blockIdx.x;
    const int token = idx[p];
    for (int v = threadIdx.x; v < VOCAB; v += blockDim.x)
        out[(size_t)p * VOCAB + v] = W[(size_t)v * VOCAB + token];
}

extern "C" void kernel_launch(void* const* d_in, const int* in_sizes, int n_in,
                              void* d_out, int out_size, void* d_ws, size_t ws_size,
                              hipStream_t stream) {
    const int*   x = (const int*)d_in[0];     // [B*T] token ids
    const float* W = (const float*)d_in[1];   // [VOCAB, VOCAB] fp32
    float* out = (float*)d_out;               // [B*T, VOCAB] fp32
    const int npos = in_sizes[0];             // 32768

    const size_t wt_bytes = (size_t)VOCAB * VOCAB * sizeof(float);

    if (ws_size >= wt_bytes) {
        float* WT = (float*)d_ws;
        dim3 tb(32, 8);
        dim3 tg((VOCAB + 31) / 32, (VOCAB + 31) / 32);
        transpose_kernel<<<tg, tb, 0, stream>>>(W, WT);
        gather_rows_kernel<<<npos, 256, 0, stream>>>(WT, x, out);
    } else {
        gather_cols_kernel<<<npos, 256, 0, stream>>>(W, x, out);
    }
}